// Round 3
// baseline (239.126 us; speedup 1.0000x reference)
//
#include <hip/hip_runtime.h>
#include <hip/hip_bf16.h>
#include <cstdint>
#include <cstddef>

// Problem constants
#define NB 64
#define NK 49
#define NT 512
#define NH 512
#define NA 49

typedef __attribute__((ext_vector_type(8))) short bf16x8;
typedef __attribute__((ext_vector_type(4))) float f32x4;

__device__ __forceinline__ float fast_exp(float x) {            // e^x
    return __builtin_amdgcn_exp2f(x * 1.4426950408889634f);
}
__device__ __forceinline__ float fast_tanh(float x) {           // 1 - 2/(e^{2x}+1)
    float e = __builtin_amdgcn_exp2f(x * 2.8853900817779268f);
    return 1.0f - 2.0f * __builtin_amdgcn_rcpf(e + 1.0f);
}
__device__ __forceinline__ short bf16rn(float x) {              // round-to-nearest-even bf16
    unsigned b = __builtin_bit_cast(unsigned, x);
    unsigned r = b + 0x7FFFu + ((b >> 16) & 1u);
    return (short)(r >> 16);
}
__device__ __forceinline__ void split_hi_lo(float x, short& hi, short& lo) {
    unsigned b = __builtin_bit_cast(unsigned, x);
    unsigned hb = b & 0xFFFF0000u;
    hi = (short)(hb >> 16);
    lo = bf16rn(x - __builtin_bit_cast(float, hb));
}

// ---------------------------------------------------------------------------
// kprep: swizzle the three A x H weight matrices into MFMA B-fragment order.
// WB[job][sel(hi/lo)][ntile(4)][kstep(16)][lane(64)][e(8)] (bf16)
//   B[k][n]: n = ntile*16 + (lane&15), k = kstep*32 + (lane>>4)*8 + e
// 24 blocks: job = bid>>3, slice = bid&7 (8192 elems each).
// ---------------------------------------------------------------------------
__global__ void kprep(const float* __restrict__ Wg, const float* __restrict__ Ws,
                      const float* __restrict__ Wv, short* __restrict__ WB) {
    const int job = blockIdx.x >> 3, slice = blockIdx.x & 7;
    const float* W = (job == 0) ? Wg : (job == 1 ? Ws : Wv);
    short* dst = WB + (size_t)job * 65536;
    const int end = (slice + 1) * 8192;
    for (int idx = slice * 8192 + threadIdx.x; idx < end; idx += 256) {
        int e    = idx & 7;
        int lane = (idx >> 3) & 63;
        int ks   = (idx >> 9) & 15;
        int nt   = (idx >> 13) & 3;
        int sel  = idx >> 15;
        int a = nt * 16 + (lane & 15);
        int h = ks * 32 + (lane >> 4) * 8 + e;
        float x = (a < NA) ? W[a * NH + h] : 0.0f;
        short hi, lo; split_hi_lo(x, hi, lo);
        dst[idx] = sel ? lo : hi;
    }
}

// ---------------------------------------------------------------------------
// kvprep: swizzle V[b] (49x512, K-dim padded to 64) into MFMA B-fragment order.
// VB[b][sel][ntile(32)][ks(2)][lane(64)][e(8)] (bf16)
//   B[k][n]: n = ntile*16 + (lane&15), k = ks*32 + (lane>>4)*8 + e ; k>=49 -> 0
// ---------------------------------------------------------------------------
__global__ void kvprep(const float* __restrict__ V, short* __restrict__ VB) {
    const int b = blockIdx.x;
    const float* Vb = V + (size_t)b * (NK * NH);
    short* dst = VB + (size_t)b * 65536;
    for (int idx = threadIdx.x; idx < 65536; idx += 256) {
        int e    = idx & 7;
        int lane = (idx >> 3) & 63;
        int ks   = (idx >> 9) & 1;
        int nt   = (idx >> 10) & 31;
        int sel  = idx >> 15;
        int n = nt * 16 + (lane & 15);
        int k = ks * 32 + (lane >> 4) * 8 + e;
        float x = (k < NK) ? Vb[(size_t)k * NH + n] : 0.0f;
        short hi, lo; split_hi_lo(x, hi, lo);
        dst[idx] = sel ? lo : hi;
    }
}

// ---------------------------------------------------------------------------
// kcv: cv[b*K+k][a] = sum_h V[b][k][h] * Wv[a][h]  (3136 rows = 49 blocks x 64)
// Same validated MFMA GEMV pattern as R2's kgemm, restricted to the V job.
// ---------------------------------------------------------------------------
__global__ __launch_bounds__(256, 4) void kcv(
        const float* __restrict__ V, const short* __restrict__ WB,
        float* __restrict__ cv) {
    const int tid  = threadIdx.x;
    const int lane = tid & 63;
    const int w    = tid >> 6;
    const int m0   = blockIdx.x * 64 + w * 16;
    const int r    = lane & 15;
    const int g    = lane >> 4;

    const float* arow = V + (size_t)(m0 + r) * NH + g * 8;
    const bf16x8* wbv = (const bf16x8*)(WB + 2 * 65536);

    f32x4 acc0 = {0.f, 0.f, 0.f, 0.f};
    f32x4 acc1 = acc0, acc2 = acc0, acc3 = acc0;

    #pragma unroll 2
    for (int ks = 0; ks < 16; ++ks) {
        float4 x0 = *(const float4*)(arow + ks * 32);
        float4 x1 = *(const float4*)(arow + ks * 32 + 4);
        bf16x8 bh0 = wbv[(0 * 16 + ks) * 64 + lane];
        bf16x8 bh1 = wbv[(1 * 16 + ks) * 64 + lane];
        bf16x8 bh2 = wbv[(2 * 16 + ks) * 64 + lane];
        bf16x8 bh3 = wbv[(3 * 16 + ks) * 64 + lane];
        bf16x8 bl0 = wbv[(4 * 16 + ks) * 64 + lane];
        bf16x8 bl1 = wbv[(5 * 16 + ks) * 64 + lane];
        bf16x8 bl2 = wbv[(6 * 16 + ks) * 64 + lane];
        bf16x8 bl3 = wbv[(7 * 16 + ks) * 64 + lane];

        bf16x8 ahi, alo;
        {
            const float xs[8] = {x0.x, x0.y, x0.z, x0.w, x1.x, x1.y, x1.z, x1.w};
            #pragma unroll
            for (int e = 0; e < 8; ++e) { short hi, lo; split_hi_lo(xs[e], hi, lo); ahi[e] = hi; alo[e] = lo; }
        }
        acc0 = __builtin_amdgcn_mfma_f32_16x16x32_bf16(ahi, bh0, acc0, 0, 0, 0);
        acc0 = __builtin_amdgcn_mfma_f32_16x16x32_bf16(alo, bh0, acc0, 0, 0, 0);
        acc0 = __builtin_amdgcn_mfma_f32_16x16x32_bf16(ahi, bl0, acc0, 0, 0, 0);
        acc1 = __builtin_amdgcn_mfma_f32_16x16x32_bf16(ahi, bh1, acc1, 0, 0, 0);
        acc1 = __builtin_amdgcn_mfma_f32_16x16x32_bf16(alo, bh1, acc1, 0, 0, 0);
        acc1 = __builtin_amdgcn_mfma_f32_16x16x32_bf16(ahi, bl1, acc1, 0, 0, 0);
        acc2 = __builtin_amdgcn_mfma_f32_16x16x32_bf16(ahi, bh2, acc2, 0, 0, 0);
        acc2 = __builtin_amdgcn_mfma_f32_16x16x32_bf16(alo, bh2, acc2, 0, 0, 0);
        acc2 = __builtin_amdgcn_mfma_f32_16x16x32_bf16(ahi, bl2, acc2, 0, 0, 0);
        acc3 = __builtin_amdgcn_mfma_f32_16x16x32_bf16(ahi, bh3, acc3, 0, 0, 0);
        acc3 = __builtin_amdgcn_mfma_f32_16x16x32_bf16(alo, bh3, acc3, 0, 0, 0);
        acc3 = __builtin_amdgcn_mfma_f32_16x16x32_bf16(ahi, bl3, acc3, 0, 0, 0);
    }

    #pragma unroll
    for (int reg = 0; reg < 4; ++reg) {
        int row = m0 + g * 4 + reg;
        float* orow = cv + (size_t)row * NA;
        orow[ 0 + r] = acc0[reg];
        orow[16 + r] = acc1[reg];
        orow[32 + r] = acc2[reg];
        if (r == 0) orow[48] = acc3[reg];
    }
}

// ---------------------------------------------------------------------------
// kfused: one block per (b, 64-row t-tile). 512 threads = 8 waves.
//  A) gh = h_rows x Wg^T, ss = s_rows x Ws^T  (MFMA, D -> LDS)
//  B) z[t][kk] = sum_a wh[a]*tanh(content)   (VALU over LDS)
//  C) softmax -> alpha (fp32 LDS + bf16 hi/lo A-frags in LDS), beta
//  D) c_t = alpha x V[b] (MFMA, B-frags from VB), blend with s_t, store
// LDS ~66 KB -> 2 blocks/CU. All register arrays statically indexed.
// ---------------------------------------------------------------------------
__global__ __launch_bounds__(512, 4) void kfused(
        const float* __restrict__ h_t, const float* __restrict__ s_t,
        const float* __restrict__ Wh,
        const short* __restrict__ WB, const short* __restrict__ VB,
        const float* __restrict__ cv_ws,
        float* __restrict__ out_chat, float* __restrict__ out_alpha,
        float* __restrict__ out_beta) {
    __shared__ float cvl[NK * 52];       // 10,192 B
    __shared__ float ghl[64 * 52];       // 13,312 B ; alpha fp32 [64][50] overlays after z
    __shared__ float ssl[64 * 52];       // 13,312 B
    __shared__ float zl[64 * 50];        // 12,800 B
    __shared__ short afrag[8192];        // 16,384 B : [sel][ks][mtile][lane][e]
    __shared__ float betal[64];          //    256 B

    const int tid  = threadIdx.x;
    const int lane = tid & 63;
    const int w    = tid >> 6;
    const int b    = blockIdx.x >> 3;
    const int t0   = (blockIdx.x & 7) * 64;
    const int r    = lane & 15;
    const int g    = lane >> 4;

    // ---- stage cv
    {
        const float* cvb = cv_ws + (size_t)b * (NK * NA);
        for (int idx = tid; idx < NK * NA; idx += 512) {
            int k = idx / NA, a = idx - k * NA;
            cvl[k * 52 + a] = cvb[idx];
        }
    }

    // ---- phase A: gh / ss GEMMs. wave w: mtile = w>>1, ntiles {2(w&1), 2(w&1)+1}
    {
        const int mtile = w >> 1, nt0 = (w & 1) * 2;
        #pragma unroll 1
        for (int job = 0; job < 2; ++job) {
            const float* in = job ? s_t : h_t;
            const bf16x8* wb = (const bf16x8*)(WB + (size_t)job * 65536);
            const float* arow = in + (size_t)(b * NT + t0 + mtile * 16 + r) * NH + g * 8;
            f32x4 acc0 = {0.f, 0.f, 0.f, 0.f};
            f32x4 acc1 = acc0;
            #pragma unroll 2
            for (int ks = 0; ks < 16; ++ks) {
                float4 x0 = *(const float4*)(arow + ks * 32);
                float4 x1 = *(const float4*)(arow + ks * 32 + 4);
                bf16x8 bh0 = wb[((0 * 4 + nt0    ) * 16 + ks) * 64 + lane];
                bf16x8 bh1 = wb[((0 * 4 + nt0 + 1) * 16 + ks) * 64 + lane];
                bf16x8 bl0 = wb[((1 * 4 + nt0    ) * 16 + ks) * 64 + lane];
                bf16x8 bl1 = wb[((1 * 4 + nt0 + 1) * 16 + ks) * 64 + lane];
                bf16x8 ahi, alo;
                {
                    const float xs[8] = {x0.x, x0.y, x0.z, x0.w, x1.x, x1.y, x1.z, x1.w};
                    #pragma unroll
                    for (int e = 0; e < 8; ++e) { short hi, lo; split_hi_lo(xs[e], hi, lo); ahi[e] = hi; alo[e] = lo; }
                }
                acc0 = __builtin_amdgcn_mfma_f32_16x16x32_bf16(ahi, bh0, acc0, 0, 0, 0);
                acc0 = __builtin_amdgcn_mfma_f32_16x16x32_bf16(alo, bh0, acc0, 0, 0, 0);
                acc0 = __builtin_amdgcn_mfma_f32_16x16x32_bf16(ahi, bl0, acc0, 0, 0, 0);
                acc1 = __builtin_amdgcn_mfma_f32_16x16x32_bf16(ahi, bh1, acc1, 0, 0, 0);
                acc1 = __builtin_amdgcn_mfma_f32_16x16x32_bf16(alo, bh1, acc1, 0, 0, 0);
                acc1 = __builtin_amdgcn_mfma_f32_16x16x32_bf16(ahi, bl1, acc1, 0, 0, 0);
            }
            float* dst = job ? ssl : ghl;
            const int c0 = nt0 * 16 + r, c1 = (nt0 + 1) * 16 + r;
            #pragma unroll
            for (int reg = 0; reg < 4; ++reg) {
                int m = mtile * 16 + g * 4 + reg;
                dst[m * 52 + c0] = acc0[reg];
                if (c1 < 52) dst[m * 52 + c1] = acc1[reg];   // ntile3 cols>=52 are discarded
            }
        }
    }
    __syncthreads();

    // ---- phase B: z
    {
        const float w48 = Wh[48];
        for (int p = tid; p < 64 * 50; p += 512) {
            int t = p / 50, kk = p - t * 50;
            const float* rowp = (kk < NK) ? (cvl + kk * 52) : (ssl + t * 52);
            const float* gp = ghl + t * 52;
            float z = 0.0f;
            #pragma unroll
            for (int q = 0; q < 12; ++q) {
                float4 rr = *(const float4*)(rowp + q * 4);
                float4 gg = *(const float4*)(gp + q * 4);
                z = fmaf(Wh[q * 4 + 0], fast_tanh(rr.x + gg.x), z);
                z = fmaf(Wh[q * 4 + 1], fast_tanh(rr.y + gg.y), z);
                z = fmaf(Wh[q * 4 + 2], fast_tanh(rr.z + gg.z), z);
                z = fmaf(Wh[q * 4 + 3], fast_tanh(rr.w + gg.w), z);
            }
            z = fmaf(w48, fast_tanh(rowp[48] + gp[48]), z);
            zl[p] = z;
        }
    }
    __syncthreads();

    // ---- phase C: softmax (wave 0, t = lane). alpha fp32 overlays ghl.
    if (tid < 64) {
        const float* zr = zl + tid * 50;
        float m49 = -1e30f;
        #pragma unroll
        for (int k = 0; k < NK; ++k) m49 = fmaxf(m49, zr[k]);
        float S = 0.0f;
        #pragma unroll
        for (int k = 0; k < NK; ++k) S += fast_exp(zr[k] - m49);
        float rS = __builtin_amdgcn_rcpf(S);

        float ze   = zr[49];
        float m50  = fmaxf(m49, ze);
        float eext = fast_exp(ze - m50);
        float beta = eext * __builtin_amdgcn_rcpf(S * fast_exp(m49 - m50) + eext);
        betal[tid] = beta;
        out_beta[(size_t)b * NT + t0 + tid] = beta;

        float* al = ghl + tid * 50;          // fp32 alpha, stride 50
        const int mt = tid >> 4, rr2 = tid & 15;
        for (int k = 0; k < 64; ++k) {
            float a = (k < NK) ? fast_exp(zr[k] - m49) * rS : 0.0f;
            if (k < NK) al[k] = a;
            short hi, lo; split_hi_lo(a, hi, lo);
            int ks = k >> 5, gg = (k & 31) >> 3, e = k & 7;
            int ln = gg * 16 + rr2;
            afrag[(((0 * 2 + ks) * 4 + mt) * 64 + ln) * 8 + e] = hi;
            afrag[(((1 * 2 + ks) * 4 + mt) * 64 + ln) * 8 + e] = lo;
        }
    }
    __syncthreads();

    // ---- alpha global write (contiguous fp32)
    {
        float* oa = out_alpha + ((size_t)b * NT + t0) * NK;
        for (int idx = tid; idx < 64 * NK; idx += 512) {
            int t = idx / NK, k = idx - t * NK;
            oa[idx] = ghl[t * 50 + k];
        }
    }

    // ---- phase D: c_t = alpha x V (MFMA), blend with s_t, store.
    // wave w owns n in [64w, 64w+64): ntiles 4w..4w+3, processed as 2 pairs.
    {
        const bf16x8* af = (const bf16x8*)afrag;
        const bf16x8* vb = (const bf16x8*)(VB + (size_t)b * 65536);
        const size_t rowb = (size_t)b * NT + t0;
        #pragma unroll 1
        for (int npair = 0; npair < 2; ++npair) {
            f32x4 acc[4][2];
            #pragma unroll
            for (int mt = 0; mt < 4; ++mt) {
                acc[mt][0] = (f32x4){0.f, 0.f, 0.f, 0.f};
                acc[mt][1] = (f32x4){0.f, 0.f, 0.f, 0.f};
            }
            #pragma unroll
            for (int ks = 0; ks < 2; ++ks) {
                bf16x8 ah[4], alo[4];
                #pragma unroll
                for (int mt = 0; mt < 4; ++mt) {
                    ah[mt]  = af[((0 * 2 + ks) * 4 + mt) * 64 + lane];
                    alo[mt] = af[((1 * 2 + ks) * 4 + mt) * 64 + lane];
                }
                #pragma unroll
                for (int j = 0; j < 2; ++j) {
                    const int nt = 4 * w + npair * 2 + j;
                    bf16x8 bh = vb[((0 * 32 + nt) * 2 + ks) * 64 + lane];
                    bf16x8 bl = vb[((1 * 32 + nt) * 2 + ks) * 64 + lane];
                    #pragma unroll
                    for (int mt = 0; mt < 4; ++mt) {
                        acc[mt][j] = __builtin_amdgcn_mfma_f32_16x16x32_bf16(ah[mt],  bh, acc[mt][j], 0, 0, 0);
                        acc[mt][j] = __builtin_amdgcn_mfma_f32_16x16x32_bf16(alo[mt], bh, acc[mt][j], 0, 0, 0);
                        acc[mt][j] = __builtin_amdgcn_mfma_f32_16x16x32_bf16(ah[mt],  bl, acc[mt][j], 0, 0, 0);
                    }
                }
            }
            #pragma unroll
            for (int j = 0; j < 2; ++j) {
                const int h0 = (4 * w + npair * 2 + j) * 16 + r;
                #pragma unroll
                for (int mt = 0; mt < 4; ++mt) {
                    #pragma unroll
                    for (int reg = 0; reg < 4; ++reg) {
                        int tloc = mt * 16 + g * 4 + reg;
                        float bt = betal[tloc];
                        size_t off = (rowb + tloc) * NH + h0;
                        float s = s_t[off];
                        float c = acc[mt][j][reg];
                        out_chat[off] = fmaf(bt, s - c, c);   // bt*s + (1-bt)*c
                    }
                }
            }
        }
    }
}

// ---------------------------------------------------------------------------
extern "C" void kernel_launch(void* const* d_in, const int* in_sizes, int n_in,
                              void* d_out, int out_size, void* d_ws, size_t ws_size,
                              hipStream_t stream) {
    const float* V   = (const float*)d_in[0];
    const float* h_t = (const float*)d_in[1];
    const float* s_t = (const float*)d_in[2];
    const float* Wv  = (const float*)d_in[3];
    const float* Wg  = (const float*)d_in[4];
    const float* Ws  = (const float*)d_in[5];
    const float* Wh  = (const float*)d_in[6];

    float* out = (float*)d_out;
    float* out_chat  = out;                                   // B*T*H
    float* out_alpha = out + (size_t)NB * NT * NH;            // B*T*K
    float* out_beta  = out_alpha + (size_t)NB * NT * NK;      // B*T

    // workspace: WB 3*65536 bf16 (384 KB) | VB 64*65536 bf16 (8 MB) | cv (614 KB)
    short* WB = (short*)d_ws;
    short* VB = WB + (size_t)3 * 65536;
    float* cv = (float*)(VB + (size_t)64 * 65536);

    kprep<<<24, 256, 0, stream>>>(Wg, Ws, Wv, WB);
    kvprep<<<64, 256, 0, stream>>>(V, VB);
    kcv<<<49, 256, 0, stream>>>(V, WB, cv);
    kfused<<<NB * 8, 512, 0, stream>>>(h_t, s_t, Wh, WB, VB, cv,
                                       out_chat, out_alpha, out_beta);
}

// Round 4
// 103.916 us; speedup vs baseline: 2.3012x; 2.3012x over previous
//
#include <hip/hip_runtime.h>
#include <hip/hip_bf16.h>
#include <cstdint>
#include <cstddef>

// Problem constants
#define NB 64
#define NK 49
#define NT 512
#define NH 512
#define NA 49

typedef __attribute__((ext_vector_type(8))) short bf16x8;
typedef __attribute__((ext_vector_type(4))) float f32x4;

__device__ __forceinline__ float fast_exp(float x) {            // e^x
    return __builtin_amdgcn_exp2f(x * 1.4426950408889634f);
}
__device__ __forceinline__ float fast_tanh(float x) {           // 1 - 2/(e^{2x}+1)
    float e = __builtin_amdgcn_exp2f(x * 2.8853900817779268f);
    return 1.0f - 2.0f * __builtin_amdgcn_rcpf(e + 1.0f);
}
__device__ __forceinline__ short bf16rn(float x) {              // round-to-nearest-even bf16
    unsigned b = __builtin_bit_cast(unsigned, x);
    unsigned r = b + 0x7FFFu + ((b >> 16) & 1u);
    return (short)(r >> 16);
}
__device__ __forceinline__ void split_hi_lo(float x, short& hi, short& lo) {
    unsigned b = __builtin_bit_cast(unsigned, x);
    unsigned hb = b & 0xFFFF0000u;
    hi = (short)(hb >> 16);
    lo = bf16rn(x - __builtin_bit_cast(float, hb));
}

// ---------------------------------------------------------------------------
// kprep: swizzle the three A x H weight matrices into MFMA B-fragment order.
// WB[job][sel(hi/lo)][ntile(4)][kstep(16)][lane(64)][e(8)] (bf16)
//   B[k][n]: n = ntile*16 + (lane&15), k = kstep*32 + (lane>>4)*8 + e
// ---------------------------------------------------------------------------
__global__ void kprep(const float* __restrict__ Wg, const float* __restrict__ Ws,
                      const float* __restrict__ Wv, short* __restrict__ WB) {
    const int job = blockIdx.x >> 3, slice = blockIdx.x & 7;
    const float* W = (job == 0) ? Wg : (job == 1 ? Ws : Wv);
    short* dst = WB + (size_t)job * 65536;
    const int end = (slice + 1) * 8192;
    for (int idx = slice * 8192 + threadIdx.x; idx < end; idx += 256) {
        int e    = idx & 7;
        int lane = (idx >> 3) & 63;
        int ks   = (idx >> 9) & 15;
        int nt   = (idx >> 13) & 3;
        int sel  = idx >> 15;
        int a = nt * 16 + (lane & 15);
        int h = ks * 32 + (lane >> 4) * 8 + e;
        float x = (a < NA) ? W[a * NH + h] : 0.0f;
        short hi, lo; split_hi_lo(x, hi, lo);
        dst[idx] = sel ? lo : hi;
    }
}

// ---------------------------------------------------------------------------
// kvprep: V[b] -> single-bf16 MFMA B-fragments, coalesced via LDS staging.
// VB[b][ntile(32)][ks(2)][lane(64)][e(8)] (bf16), 32768 per b (4 MB total)
//   B[k][n]: n = ntile*16 + (lane&15), k = ks*32 + (lane>>4)*8 + e ; k>=49 -> 0
// Block = (b, 64-col slice): stage V[0..49)[h0..h0+64) coalesced, emit frags.
// ---------------------------------------------------------------------------
__global__ __launch_bounds__(256, 8) void kvprep(const float* __restrict__ V,
                                                 short* __restrict__ VB) {
    __shared__ float vl[NK * 64];        // 12.5 KB
    const int b  = blockIdx.x >> 3;
    const int sl = blockIdx.x & 7;       // 8 slices of 64 h-cols
    const int h0 = sl * 64;
    const float* Vb = V + (size_t)b * (NK * NH);

    for (int idx = threadIdx.x; idx < NK * 64; idx += 256) {
        int k = idx >> 6, c = idx & 63;
        vl[idx] = Vb[(size_t)k * NH + h0 + c];   // 256B contiguous per k-row
    }
    __syncthreads();

    short* dst = VB + (size_t)b * 32768;
    for (int idx = threadIdx.x; idx < 4096; idx += 256) {
        int e    = idx & 7;
        int lane = (idx >> 3) & 63;
        int ks   = (idx >> 9) & 1;
        int ntl  = idx >> 10;            // 0..3 within slice
        int k = ks * 32 + (lane >> 4) * 8 + e;
        int c = ntl * 16 + (lane & 15);
        float x = (k < NK) ? vl[k * 64 + c] : 0.0f;
        dst[((size_t)(sl * 4 + ntl) * 2 + ks) * 512 + lane * 8 + e] = bf16rn(x);
    }
}

// ---------------------------------------------------------------------------
// kcv: cv[b*K+k][a] = sum_h V[b][k][h] * Wv[a][h]  (3136 rows = 49 blocks x 64)
// Validated R2/R3 MFMA GEMV pattern (hi/lo split, 3-term).
// ---------------------------------------------------------------------------
__global__ __launch_bounds__(256, 4) void kcv(
        const float* __restrict__ V, const short* __restrict__ WB,
        float* __restrict__ cv) {
    const int tid  = threadIdx.x;
    const int lane = tid & 63;
    const int w    = tid >> 6;
    const int m0   = blockIdx.x * 64 + w * 16;
    const int r    = lane & 15;
    const int g    = lane >> 4;

    const float* arow = V + (size_t)(m0 + r) * NH + g * 8;
    const bf16x8* wbv = (const bf16x8*)(WB + 2 * 65536);

    f32x4 acc0 = {0.f, 0.f, 0.f, 0.f};
    f32x4 acc1 = acc0, acc2 = acc0, acc3 = acc0;

    #pragma unroll 2
    for (int ks = 0; ks < 16; ++ks) {
        float4 x0 = *(const float4*)(arow + ks * 32);
        float4 x1 = *(const float4*)(arow + ks * 32 + 4);
        bf16x8 bh0 = wbv[(0 * 16 + ks) * 64 + lane];
        bf16x8 bh1 = wbv[(1 * 16 + ks) * 64 + lane];
        bf16x8 bh2 = wbv[(2 * 16 + ks) * 64 + lane];
        bf16x8 bh3 = wbv[(3 * 16 + ks) * 64 + lane];
        bf16x8 bl0 = wbv[(4 * 16 + ks) * 64 + lane];
        bf16x8 bl1 = wbv[(5 * 16 + ks) * 64 + lane];
        bf16x8 bl2 = wbv[(6 * 16 + ks) * 64 + lane];
        bf16x8 bl3 = wbv[(7 * 16 + ks) * 64 + lane];

        bf16x8 ahi, alo;
        {
            const float xs[8] = {x0.x, x0.y, x0.z, x0.w, x1.x, x1.y, x1.z, x1.w};
            #pragma unroll
            for (int e = 0; e < 8; ++e) { short hi, lo; split_hi_lo(xs[e], hi, lo); ahi[e] = hi; alo[e] = lo; }
        }
        acc0 = __builtin_amdgcn_mfma_f32_16x16x32_bf16(ahi, bh0, acc0, 0, 0, 0);
        acc0 = __builtin_amdgcn_mfma_f32_16x16x32_bf16(alo, bh0, acc0, 0, 0, 0);
        acc0 = __builtin_amdgcn_mfma_f32_16x16x32_bf16(ahi, bl0, acc0, 0, 0, 0);
        acc1 = __builtin_amdgcn_mfma_f32_16x16x32_bf16(ahi, bh1, acc1, 0, 0, 0);
        acc1 = __builtin_amdgcn_mfma_f32_16x16x32_bf16(alo, bh1, acc1, 0, 0, 0);
        acc1 = __builtin_amdgcn_mfma_f32_16x16x32_bf16(ahi, bl1, acc1, 0, 0, 0);
        acc2 = __builtin_amdgcn_mfma_f32_16x16x32_bf16(ahi, bh2, acc2, 0, 0, 0);
        acc2 = __builtin_amdgcn_mfma_f32_16x16x32_bf16(alo, bh2, acc2, 0, 0, 0);
        acc2 = __builtin_amdgcn_mfma_f32_16x16x32_bf16(ahi, bl2, acc2, 0, 0, 0);
        acc3 = __builtin_amdgcn_mfma_f32_16x16x32_bf16(ahi, bh3, acc3, 0, 0, 0);
        acc3 = __builtin_amdgcn_mfma_f32_16x16x32_bf16(alo, bh3, acc3, 0, 0, 0);
        acc3 = __builtin_amdgcn_mfma_f32_16x16x32_bf16(ahi, bl3, acc3, 0, 0, 0);
    }

    #pragma unroll
    for (int reg = 0; reg < 4; ++reg) {
        int row = m0 + g * 4 + reg;
        float* orow = cv + (size_t)row * NA;
        orow[ 0 + r] = acc0[reg];
        orow[16 + r] = acc1[reg];
        orow[32 + r] = acc2[reg];
        if (r == 0) orow[48] = acc3[reg];
    }
}

// ---------------------------------------------------------------------------
// kfused: one block per (b, 32-row t-tile). 256 threads = 4 waves.
//  A) gh/ss MFMA GEMM -> LDS   (wave w: job = w>>1, mtile = w&1)
//  B) z[t][kk] tanh-dot (VALU)
//  C) softmax -> alpha fp32 (overlays ghl) + bf16 A-frags, beta
//  D) c_t = alpha x V (single-bf16 MFMA, B-frags from VB), blend, store
// LDS ~34 KB, launch_bounds(256,4) -> 128 VGPR cap, 4 blocks/CU.
// ---------------------------------------------------------------------------
__global__ __launch_bounds__(256, 4) void kfused(
        const float* __restrict__ h_t, const float* __restrict__ s_t,
        const float* __restrict__ Wh,
        const short* __restrict__ WB, const short* __restrict__ VB,
        const float* __restrict__ cv_ws,
        float* __restrict__ out_chat, float* __restrict__ out_alpha,
        float* __restrict__ out_beta) {
    __shared__ float cvl[NK * 52];       // 10,192 B
    __shared__ float ghl[32 * 52];       //  6,656 B ; alpha fp32 [32][50] overlays after B
    __shared__ float ssl[32 * 52];       //  6,656 B
    __shared__ float zl[32 * 50];        //  6,400 B
    __shared__ short afrag[2048];        //  4,096 B : [ks(2)][mt(2)][lane(64)][e(8)]
    __shared__ float whl[52];            //    208 B
    __shared__ float betal[32];          //    128 B

    const int tid  = threadIdx.x;
    const int lane = tid & 63;
    const int w    = tid >> 6;
    const int b    = blockIdx.x >> 4;
    const int t0   = (blockIdx.x & 15) * 32;
    const int r    = lane & 15;
    const int g    = lane >> 4;

    // ---- stage cv + wh
    {
        const float* cvb = cv_ws + (size_t)b * (NK * NA);
        for (int idx = tid; idx < NK * NA; idx += 256) {
            int k = idx / NA, a = idx - k * NA;
            cvl[k * 52 + a] = cvb[idx];
        }
        if (tid < NA) whl[tid] = Wh[tid];
    }

    // ---- phase A: gh / ss GEMM. wave w: job = w>>1, mtile = w&1, ntiles 0..3
    {
        const int job = w >> 1, mtile = w & 1;
        const float* in = job ? s_t : h_t;
        const bf16x8* wb = (const bf16x8*)(WB + (size_t)job * 65536);
        const float* arow = in + (size_t)(b * NT + t0 + mtile * 16 + r) * NH + g * 8;
        f32x4 acc0 = {0.f, 0.f, 0.f, 0.f};
        f32x4 acc1 = acc0, acc2 = acc0, acc3 = acc0;
        #pragma unroll 2
        for (int ks = 0; ks < 16; ++ks) {
            float4 x0 = *(const float4*)(arow + ks * 32);
            float4 x1 = *(const float4*)(arow + ks * 32 + 4);
            bf16x8 bh0 = wb[(( 0 + 0) * 16 + ks) * 64 + lane];
            bf16x8 bh1 = wb[(( 0 + 1) * 16 + ks) * 64 + lane];
            bf16x8 bh2 = wb[(( 0 + 2) * 16 + ks) * 64 + lane];
            bf16x8 bh3 = wb[(( 0 + 3) * 16 + ks) * 64 + lane];
            bf16x8 bl0 = wb[(( 4 + 0) * 16 + ks) * 64 + lane];
            bf16x8 bl1 = wb[(( 4 + 1) * 16 + ks) * 64 + lane];
            bf16x8 bl2 = wb[(( 4 + 2) * 16 + ks) * 64 + lane];
            bf16x8 bl3 = wb[(( 4 + 3) * 16 + ks) * 64 + lane];
            bf16x8 ahi, alo;
            {
                const float xs[8] = {x0.x, x0.y, x0.z, x0.w, x1.x, x1.y, x1.z, x1.w};
                #pragma unroll
                for (int e = 0; e < 8; ++e) { short hi, lo; split_hi_lo(xs[e], hi, lo); ahi[e] = hi; alo[e] = lo; }
            }
            acc0 = __builtin_amdgcn_mfma_f32_16x16x32_bf16(ahi, bh0, acc0, 0, 0, 0);
            acc0 = __builtin_amdgcn_mfma_f32_16x16x32_bf16(alo, bh0, acc0, 0, 0, 0);
            acc0 = __builtin_amdgcn_mfma_f32_16x16x32_bf16(ahi, bl0, acc0, 0, 0, 0);
            acc1 = __builtin_amdgcn_mfma_f32_16x16x32_bf16(ahi, bh1, acc1, 0, 0, 0);
            acc1 = __builtin_amdgcn_mfma_f32_16x16x32_bf16(alo, bh1, acc1, 0, 0, 0);
            acc1 = __builtin_amdgcn_mfma_f32_16x16x32_bf16(ahi, bl1, acc1, 0, 0, 0);
            acc2 = __builtin_amdgcn_mfma_f32_16x16x32_bf16(ahi, bh2, acc2, 0, 0, 0);
            acc2 = __builtin_amdgcn_mfma_f32_16x16x32_bf16(alo, bh2, acc2, 0, 0, 0);
            acc2 = __builtin_amdgcn_mfma_f32_16x16x32_bf16(ahi, bl2, acc2, 0, 0, 0);
            acc3 = __builtin_amdgcn_mfma_f32_16x16x32_bf16(ahi, bh3, acc3, 0, 0, 0);
            acc3 = __builtin_amdgcn_mfma_f32_16x16x32_bf16(alo, bh3, acc3, 0, 0, 0);
            acc3 = __builtin_amdgcn_mfma_f32_16x16x32_bf16(ahi, bl3, acc3, 0, 0, 0);
        }
        float* dst = (w >> 1) ? ssl : ghl;
        #pragma unroll
        for (int reg = 0; reg < 4; ++reg) {
            int m = mtile * 16 + g * 4 + reg;
            dst[m * 52 +  0 + r] = acc0[reg];
            dst[m * 52 + 16 + r] = acc1[reg];
            dst[m * 52 + 32 + r] = acc2[reg];
            if (r < 4) dst[m * 52 + 48 + r] = acc3[reg];  // only col 48 used downstream
        }
    }
    __syncthreads();

    // ---- phase B: z
    {
        const float w48 = whl[48];
        for (int p = tid; p < 32 * 50; p += 256) {
            int t = p / 50, kk = p - t * 50;
            const float* rowp = (kk < NK) ? (cvl + kk * 52) : (ssl + t * 52);
            const float* gp = ghl + t * 52;
            float z = 0.0f;
            #pragma unroll
            for (int q = 0; q < 12; ++q) {
                float4 rr = *(const float4*)(rowp + q * 4);
                float4 gg = *(const float4*)(gp + q * 4);
                z = fmaf(whl[q * 4 + 0], fast_tanh(rr.x + gg.x), z);
                z = fmaf(whl[q * 4 + 1], fast_tanh(rr.y + gg.y), z);
                z = fmaf(whl[q * 4 + 2], fast_tanh(rr.z + gg.z), z);
                z = fmaf(whl[q * 4 + 3], fast_tanh(rr.w + gg.w), z);
            }
            z = fmaf(w48, fast_tanh(rowp[48] + gp[48]), z);
            zl[p] = z;
        }
    }
    __syncthreads();

    // ---- phase C: softmax (t = tid, 32 rows). alpha fp32 overlays ghl.
    if (tid < 32) {
        const float* zr = zl + tid * 50;
        float m49 = -1e30f;
        #pragma unroll
        for (int k = 0; k < NK; ++k) m49 = fmaxf(m49, zr[k]);
        float S = 0.0f;
        #pragma unroll
        for (int k = 0; k < NK; ++k) S += fast_exp(zr[k] - m49);
        float rS = __builtin_amdgcn_rcpf(S);

        float ze   = zr[49];
        float m50  = fmaxf(m49, ze);
        float eext = fast_exp(ze - m50);
        float beta = eext * __builtin_amdgcn_rcpf(S * fast_exp(m49 - m50) + eext);
        betal[tid] = beta;
        out_beta[(size_t)b * NT + t0 + tid] = beta;

        float* al = ghl + tid * 50;          // fp32 alpha, stride 50
        const int mt = tid >> 4, rr2 = tid & 15;
        for (int k = 0; k < 64; ++k) {
            float a = (k < NK) ? fast_exp(zr[k] - m49) * rS : 0.0f;
            if (k < NK) al[k] = a;
            int ks = k >> 5, gg = (k & 31) >> 3, e = k & 7;
            int ln = gg * 16 + rr2;
            afrag[((ks * 2 + mt) * 64 + ln) * 8 + e] = bf16rn(a);
        }
    }
    __syncthreads();

    // ---- alpha global write (contiguous fp32)
    {
        float* oa = out_alpha + ((size_t)b * NT + t0) * NK;
        for (int idx = tid; idx < 32 * NK; idx += 256) {
            int t = idx / NK, k = idx - t * NK;
            oa[idx] = ghl[t * 50 + k];
        }
    }

    // ---- phase D: c_t = alpha x V (single bf16), blend with s_t, store.
    // wave w owns ntiles 8w .. 8w+7 (128 h-cols).
    {
        const bf16x8* af = (const bf16x8*)afrag;
        const bf16x8* vb = (const bf16x8*)(VB + (size_t)b * 32768);
        const size_t rowb = (size_t)b * NT + t0;

        bf16x8 a00 = af[(0 * 2 + 0) * 64 + lane];   // [ks][mt]
        bf16x8 a01 = af[(0 * 2 + 1) * 64 + lane];
        bf16x8 a10 = af[(1 * 2 + 0) * 64 + lane];
        bf16x8 a11 = af[(1 * 2 + 1) * 64 + lane];

        #pragma unroll 2
        for (int ntl = 0; ntl < 8; ++ntl) {
            const int nt = w * 8 + ntl;
            bf16x8 b0 = vb[(nt * 2 + 0) * 64 + lane];
            bf16x8 b1 = vb[(nt * 2 + 1) * 64 + lane];
            f32x4 acc0 = {0.f, 0.f, 0.f, 0.f};
            f32x4 acc1 = acc0;
            acc0 = __builtin_amdgcn_mfma_f32_16x16x32_bf16(a00, b0, acc0, 0, 0, 0);
            acc0 = __builtin_amdgcn_mfma_f32_16x16x32_bf16(a10, b1, acc0, 0, 0, 0);
            acc1 = __builtin_amdgcn_mfma_f32_16x16x32_bf16(a01, b0, acc1, 0, 0, 0);
            acc1 = __builtin_amdgcn_mfma_f32_16x16x32_bf16(a11, b1, acc1, 0, 0, 0);

            const int h0 = nt * 16 + r;
            #pragma unroll
            for (int reg = 0; reg < 4; ++reg) {
                {   // mt 0
                    int tloc = g * 4 + reg;
                    float bt = betal[tloc];
                    size_t off = (rowb + tloc) * NH + h0;
                    float s = s_t[off];
                    out_chat[off] = fmaf(bt, s - acc0[reg], acc0[reg]);
                }
                {   // mt 1
                    int tloc = 16 + g * 4 + reg;
                    float bt = betal[tloc];
                    size_t off = (rowb + tloc) * NH + h0;
                    float s = s_t[off];
                    out_chat[off] = fmaf(bt, s - acc1[reg], acc1[reg]);
                }
            }
        }
    }
}

// ---------------------------------------------------------------------------
extern "C" void kernel_launch(void* const* d_in, const int* in_sizes, int n_in,
                              void* d_out, int out_size, void* d_ws, size_t ws_size,
                              hipStream_t stream) {
    const float* V   = (const float*)d_in[0];
    const float* h_t = (const float*)d_in[1];
    const float* s_t = (const float*)d_in[2];
    const float* Wv  = (const float*)d_in[3];
    const float* Wg  = (const float*)d_in[4];
    const float* Ws  = (const float*)d_in[5];
    const float* Wh  = (const float*)d_in[6];

    float* out = (float*)d_out;
    float* out_chat  = out;                                   // B*T*H
    float* out_alpha = out + (size_t)NB * NT * NH;            // B*T*K
    float* out_beta  = out_alpha + (size_t)NB * NT * NK;      // B*T

    // workspace: WB 3*65536 bf16 (384 KB) | VB 64*32768 bf16 (4 MB) | cv (614 KB)
    short* WB = (short*)d_ws;
    short* VB = WB + (size_t)3 * 65536;
    float* cv = (float*)(VB + (size_t)64 * 32768);

    kprep<<<24, 256, 0, stream>>>(Wg, Ws, Wv, WB);
    kvprep<<<NB * 8, 256, 0, stream>>>(V, VB);
    kcv<<<49, 256, 0, stream>>>(V, WB, cv);
    kfused<<<NB * 16, 256, 0, stream>>>(h_t, s_t, Wh, WB, VB, cv,
                                        out_chat, out_alpha, out_beta);
}